// Round 11
// baseline (478.770 us; speedup 1.0000x reference)
//
#include <hip/hip_runtime.h>
#include <math.h>

#define L 8
#define N 32768
#define H 404
#define D 128
#define F 532
#define KT 9              // K-tiles of 64 (64*9=576; B cols >= 532 are zero)
#define GRU_BLK 101

typedef __attribute__((ext_vector_type(8))) _Float16 half8;
typedef __attribute__((ext_vector_type(4))) float f32x4;
typedef __attribute__((address_space(3))) unsigned int as3_u32;
typedef __attribute__((address_space(1))) unsigned int as1_u32;

// workspace layout (float offsets)
#define WS_WH2     0                        // 9*64*128 fp16 = 36864 floats (pre-swizzled B)
#define WS_HMAXK   36864                    // 8*128 uint keys
#define WS_HSEL    37888                    // 7*128
#define WS_GI      38784                    // 8*1212
#define WS_HBUF    48480                    // 2*404
#define WS_HS      49288                    // 128
#define WS_SCAL    49416                    // [1]=M, [2]=S
#define WS_CNT     49420                    // cntA, cntG, cntB, pad
#define WS_PM      49424                    // 1024
#define WS_PS      50448                    // 1024
#define WS_LOGITS  51472                    // 32769
#define WS_HNTS7   84992                    // 32768*128 fp32

__device__ __forceinline__ unsigned encf(float f) {
    unsigned u = __float_as_uint(f);
    return (u & 0x80000000u) ? ~u : (u | 0x80000000u);
}
__device__ __forceinline__ float decf(unsigned u) {
    unsigned b = (u & 0x80000000u) ? (u ^ 0x80000000u) : ~u;
    return __uint_as_float(b);
}
__device__ __forceinline__ float sigmoidf_(float x) {
    return 1.0f / (1.0f + __expf(-x));
}
__device__ __forceinline__ unsigned pk_f16(float a, float b) {
    auto h = __builtin_amdgcn_cvt_pkrtz(a, b);
    return *(unsigned*)&h;
}
__device__ __forceinline__ half8 pack8(float4 x0, float4 x1) {
    uint4 u = { pk_f16(x0.x, x0.y), pk_f16(x0.z, x0.w),
                pk_f16(x1.x, x1.y), pk_f16(x1.z, x1.w) };
    return *(half8*)&u;
}
__device__ __forceinline__ void gld16(const void* g, void* l) {
    __builtin_amdgcn_global_load_lds((const as1_u32*)g, (as3_u32*)l, 16, 0, 0);
}
__device__ __forceinline__ float aload(const float* p) {
    return __hip_atomic_load(p, __ATOMIC_RELAXED, __HIP_MEMORY_SCOPE_AGENT);
}
__device__ __forceinline__ void astore(float* p, float v) {
    __hip_atomic_store(p, v, __ATOMIC_RELAXED, __HIP_MEMORY_SCOPE_AGENT);
}
// device-wide barrier: each block adds once; wait for target
__device__ __forceinline__ void gbar(unsigned* cnt, unsigned target) {
    __syncthreads();
    if (threadIdx.x == 0) {
        __hip_atomic_fetch_add(cnt, 1u, __ATOMIC_RELEASE, __HIP_MEMORY_SCOPE_AGENT);
        while (__hip_atomic_load(cnt, __ATOMIC_ACQUIRE, __HIP_MEMORY_SCOPE_AGENT) < target)
            __builtin_amdgcn_s_sleep(2);
    }
    __syncthreads();
}

// ---- prep: pre-swizzled fp16 B tiles; init keys + counters ----
__global__ void k_prep(const float* __restrict__ Wfa, unsigned short* __restrict__ wh2,
                       unsigned* __restrict__ keys, unsigned* __restrict__ cnts) {
    int i = blockIdx.x * 256 + threadIdx.x;
    if (i < L * D) keys[i] = 0u;
    if (i >= 2000 && i < 2003) cnts[i - 2000] = 0u;
    if (i >= KT * 128 * 8) return;
    int kt = i / (128 * 8);
    int rem = i - kt * 128 * 8;
    int c = rem >> 3, j = rem & 7;
    int k0 = kt * 64 + (j ^ (c & 7)) * 8;
    unsigned short v[8];
#pragma unroll
    for (int e = 0; e < 8; ++e) {
        int k = k0 + e;
        float x = (k < F) ? Wfa[c * F + k] : 0.0f;
        _Float16 h = (_Float16)x;
        v[e] = *(unsigned short*)&h;
    }
    *(uint4*)(wh2 + (long)i * 8) = *(uint4*)v;
}

// ---- big einsum (r9 structure, proven) + hnts7 store for hop 7 ----
__global__ __launch_bounds__(256, 3)
void k_big(const float* __restrict__ nb, const unsigned short* __restrict__ wh2,
           const float* __restrict__ bfa, const int* __restrict__ aid,
           unsigned* __restrict__ hmaxk, float* __restrict__ hsel,
           float* __restrict__ hnts7) {
    __shared__ float As[128 * 64];          // 32 KB
    __shared__ unsigned short Bs[128 * 64]; // 16 KB

    const int bid = blockIdx.x;
    const int l_hop = bid >> 8;
    const int row0 = (bid & 255) * 128;
    const int tid = threadIdx.x;
    const int lane = tid & 63, w = tid >> 6;
    const int wm = w >> 1, wn = w & 1;
    const int lr = lane & 15, kg = lane >> 4;

    const float* xbase = nb + ((long)l_hop * N + row0) * F;

    f32x4 acc[4][4];
    float bv[4];
#pragma unroll
    for (int n = 0; n < 4; ++n) bv[n] = bfa[wn * 64 + n * 16 + lr];
#pragma unroll
    for (int m = 0; m < 4; ++m)
#pragma unroll
        for (int n = 0; n < 4; ++n) {
            acc[m][n][0] = bv[n]; acc[m][n][1] = bv[n];
            acc[m][n][2] = bv[n]; acc[m][n][3] = bv[n];
        }

    const int srow = lane >> 4;
    const int scp  = lane & 15;

    for (int kt = 0; kt < KT; ++kt) {
        const int fc = kt * 64;
        __syncthreads();
#pragma unroll
        for (int it = 0; it < 8; ++it) {
            int rbase = it * 16 + w * 4;
            int row = rbase + srow;
            int cg = scp ^ (row & 7);
            int col0 = fc + cg * 4;
            const float* src = xbase + (long)row * F + ((col0 < F) ? col0 : 0);
            gld16(src, (char*)As + rbase * 256);
        }
#pragma unroll
        for (int it = 0; it < 4; ++it) {
            int rb = it * 32 + w * 8;
            const char* src = (const char*)wh2 + (long)kt * 16384 + rb * 128 + lane * 16;
            gld16(src, (char*)Bs + rb * 128);
        }
        __syncthreads();

#pragma unroll
        for (int ks = 0; ks < 2; ++ks) {
            half8 b[4];
#pragma unroll
            for (int n = 0; n < 4; ++n) {
                int col = wn * 64 + n * 16 + lr;
                int ch = (ks * 4 + kg) ^ (col & 7);
                b[n] = *(const half8*)((const char*)Bs + col * 128 + ch * 16);
            }
#pragma unroll
            for (int m = 0; m < 4; ++m) {
                int row = wm * 64 + m * 16 + lr;
                int c0 = ks * 8 + kg * 2;
                const char* base = (const char*)As + row * 256;
                float4 x0 = *(const float4*)(base + (((c0)     ^ (row & 7)) << 4));
                float4 x1 = *(const float4*)(base + (((c0 + 1) ^ (row & 7)) << 4));
                half8 a = pack8(x0, x1);
#pragma unroll
                for (int n = 0; n < 4; ++n)
                    acc[m][n] = __builtin_amdgcn_mfma_f32_16x16x32_f16(a, b[n], acc[m][n], 0, 0, 0);
            }
        }
    }

    __syncthreads();

    if (l_hop < L - 1) {
        int br = aid[l_hop] - row0;
        if (br >= 0 && br < 128 && (br >> 6) == wm && ((br >> 2) & 3) == kg) {
            int msel = (br >> 4) & 3, rsel = br & 3;
#pragma unroll
            for (int n = 0; n < 4; ++n) {
                float vsel = 0.f;
#pragma unroll
                for (int m = 0; m < 4; ++m)
#pragma unroll
                    for (int r = 0; r < 4; ++r)
                        if (m == msel && r == rsel) vsel = acc[m][n][r];
                hsel[l_hop * D + wn * 64 + n * 16 + lr] = vsel;
            }
        }
    } else {
        // hop 7: persist full hnts rows (bias included) for uks
        float* hbase = hnts7 + (long)row0 * D;
#pragma unroll
        for (int m = 0; m < 4; ++m) {
            int rb = wm * 64 + m * 16 + kg * 4;
#pragma unroll
            for (int r = 0; r < 4; ++r) {
                float* rowp = hbase + (long)(rb + r) * D + wn * 64 + lr;
#pragma unroll
                for (int n = 0; n < 4; ++n)
                    rowp[n * 16] = acc[m][n][r];
            }
        }
    }

    float cmax[4];
#pragma unroll
    for (int n = 0; n < 4; ++n) {
        float m0 = acc[0][n][0];
#pragma unroll
        for (int m = 0; m < 4; ++m)
#pragma unroll
            for (int r = 0; r < 4; ++r) m0 = fmaxf(m0, acc[m][n][r]);
        m0 = fmaxf(m0, __shfl_xor(m0, 16, 64));
        m0 = fmaxf(m0, __shfl_xor(m0, 32, 64));
        cmax[n] = m0;
    }
    float* wmaxp = (float*)As;
    if (kg == 0) {
#pragma unroll
        for (int n = 0; n < 4; ++n)
            wmaxp[wm * 128 + wn * 64 + n * 16 + lr] = cmax[n];
    }
    __syncthreads();
    if (tid < 128) {
        float mval = fmaxf(wmaxp[tid], wmaxp[128 + tid]);
        atomicMax(&hmaxk[l_hop * D + tid], encf(mval));
    }
}

// ---- fused chain A: gi -> GRU(8 steps) -> hSt -> u0 ; 303 blocks ----
__global__ __launch_bounds__(256)
void k_fuseA(const float* __restrict__ Wih, const float* __restrict__ bih,
             const float* __restrict__ pn, const unsigned* __restrict__ hmaxk,
             const float* __restrict__ hsel, const float* __restrict__ Whh,
             const float* __restrict__ bhh, const float* __restrict__ query,
             const float* __restrict__ Wfs, const float* __restrict__ bfs,
             const float* __restrict__ Wfp, const float* __restrict__ bfp,
             float* __restrict__ gi, float* __restrict__ hbuf,
             float* __restrict__ hs_ws, float* __restrict__ logits,
             unsigned* __restrict__ cnts) {
    __shared__ float xs[L][3 * D];          // 12 KB
    const int bid = blockIdx.x;
    const int tid = threadIdx.x;
    const int lane = tid & 63, w4 = tid >> 6;
    unsigned* cntA = cnts + 0;
    unsigned* cntG = cnts + 1;

    // ---- P1: gi (all 303 blocks; rows 0..1211) ----
    for (int i = tid; i < L * 3 * D; i += 256) {
        int t = i / (3 * D), k = i % (3 * D);
        float x;
        if (t == 0) {
            x = (k < 2 * D) ? 0.0f : pn[k - 2 * D];
        } else {
            if (k < D)            x = decf(hmaxk[(t - 1) * D + k]);
            else if (k < 2 * D)   x = hsel[(t - 1) * D + (k - D)];
            else                  x = pn[t * D + (k - 2 * D)];
        }
        xs[t][k] = x;
    }
    __syncthreads();
    {
        const int row = bid * 4 + w4;
        const float* wr = Wih + (long)row * 3 * D;
        float s[L];
#pragma unroll
        for (int t = 0; t < L; ++t) s[t] = 0.f;
#pragma unroll
        for (int c = 0; c < 6; ++c) {
            int k = lane + c * 64;
            float wv = wr[k];
#pragma unroll
            for (int t = 0; t < L; ++t) s[t] = fmaf(wv, xs[t][k], s[t]);
        }
#pragma unroll
        for (int t = 0; t < L; ++t)
            for (int off = 1; off < 64; off <<= 1) s[t] += __shfl_xor(s[t], off, 64);
        if (lane == 0) {
            float b = bih[row];
#pragma unroll
            for (int t = 0; t < L; ++t) astore(&gi[t * 3 * H + row], s[t] + b);
        }
    }
    gbar(cntA, 303);

    // ---- P2: GRU, blocks 0..100 (one wave per hidden j) ----
    if (bid < GRU_BLK) {
        const int j = bid * 4 + w4;
        float wr[7], wz[7], wnn[7];
#pragma unroll
        for (int c = 0; c < 7; ++c) {
            int i = lane + c * 64;
            bool ok = i < H;
            wr[c]  = ok ? Whh[(long)j * H + i]           : 0.f;
            wz[c]  = ok ? Whh[(long)(H + j) * H + i]     : 0.f;
            wnn[c] = ok ? Whh[(long)(2 * H + j) * H + i] : 0.f;
        }
        float b_r = 0.f, b_z = 0.f, b_n = 0.f;
        if (lane == 0) { b_r = bhh[j]; b_z = bhh[H + j]; b_n = bhh[2 * H + j]; }

        for (int t = 0; t < L; ++t) {
            const float* hin = (t == 0) ? query : (hbuf + ((t - 1) & 1) * H);
            float* hout = hbuf + (t & 1) * H;
            float pr = 0.f, pz = 0.f, pn2 = 0.f;
#pragma unroll
            for (int c = 0; c < 7; ++c) {
                int i = lane + c * 64;
                float hv = 0.f;
                if (i < H) hv = (t == 0) ? hin[i] : aload(hin + i);
                pr  = fmaf(wr[c],  hv, pr);
                pz  = fmaf(wz[c],  hv, pz);
                pn2 = fmaf(wnn[c], hv, pn2);
            }
            for (int off = 1; off < 64; off <<= 1) {
                pr  += __shfl_xor(pr, off, 64);
                pz  += __shfl_xor(pz, off, 64);
                pn2 += __shfl_xor(pn2, off, 64);
            }
            if (lane == 0) {
                float g0 = aload(&gi[t * 3 * H + j]);
                float g1 = aload(&gi[t * 3 * H + H + j]);
                float g2 = aload(&gi[t * 3 * H + 2 * H + j]);
                float hprev = (t == 0) ? hin[j] : aload(hin + j);
                float r  = sigmoidf_(g0 + pr + b_r);
                float z  = sigmoidf_(g1 + pz + b_z);
                float nn = tanhf(g2 + r * (pn2 + b_n));
                astore(hout + j, (1.0f - z) * nn + z * hprev);
            }
            if (t < L - 1) {
                __syncthreads();
                if (tid == 0) {
                    __hip_atomic_fetch_add(cntG, 1u, __ATOMIC_RELEASE,
                                           __HIP_MEMORY_SCOPE_AGENT);
                    unsigned target = (unsigned)GRU_BLK * (t + 1);
                    while (__hip_atomic_load(cntG, __ATOMIC_ACQUIRE,
                                             __HIP_MEMORY_SCOPE_AGENT) < target)
                        __builtin_amdgcn_s_sleep(2);
                }
                __syncthreads();
            }
        }
    }
    gbar(cntA, 2 * 303);

    // ---- P3: hSt, blocks 0..31 (d = bid*4 + w4) ----
    if (bid < 32) {
        const float* qt = hbuf + H;         // hbuf[1]
        int d = bid * 4 + w4;
        float s = 0.f;
#pragma unroll
        for (int c = 0; c < 7; ++c) {
            int i = lane + c * 64;
            if (i < H) s = fmaf(aload(qt + i), Wfs[(long)d * H + i], s);
        }
        for (int off = 1; off < 64; off <<= 1) s += __shfl_xor(s, off, 64);
        if (lane == 0) astore(&hs_ws[d], s + bfs[d]);
    }
    gbar(cntA, 3 * 303);

    // ---- P4: u0 (block 0, wave 0) ----
    if (bid == 0 && w4 == 0) {
        float s = fmaf(aload(&hs_ws[lane]),      Wfp[lane],       0.f);
        s = fmaf(aload(&hs_ws[lane + 64]),       Wfp[lane + 64],  s);
        s = fmaf(decf(hmaxk[(L - 1) * D + lane]),      Wfp[D + lane],      s);
        s = fmaf(decf(hmaxk[(L - 1) * D + lane + 64]), Wfp[D + lane + 64], s);
        for (int off = 1; off < 64; off <<= 1) s += __shfl_xor(s, off, 64);
        if (lane == 0) astore(&logits[0], s + bfp[0]);
    }
}

// ---- fused chain B: uks (from hnts7) + softmax ; 1024 blocks ----
__global__ __launch_bounds__(256)
void k_fuseB(const float* __restrict__ hnts7, const float* __restrict__ hs_ws,
             float* __restrict__ logits, float* __restrict__ pm,
             float* __restrict__ ps, float* __restrict__ scal,
             float* __restrict__ out, unsigned* __restrict__ cnts) {
    __shared__ float wpm[4], wps[4], rm[4], rs[4];
    const int bid = blockIdx.x;
    const int tid = threadIdx.x;
    const int lane = tid & 63, w4 = tid >> 6;
    unsigned* cntB = cnts + 2;

    // ---- P1: 32 logits per block + online partial ----
    {
        float h0 = hs_ws[lane * 2];          // cross-kernel: plain loads fine
        float h1 = hs_ws[lane * 2 + 1];
        float mw = -3.4e38f, sw = 0.f;
#pragma unroll
        for (int r = 0; r < 8; ++r) {
            int n = bid * 32 + w4 * 8 + r;
            float2 x = *(const float2*)(hnts7 + (long)n * D + lane * 2);
            float s = h0 * x.x + h1 * x.y;
            for (int off = 1; off < 64; off <<= 1) s += __shfl_xor(s, off, 64);
            if (lane == 0) {
                astore(&logits[1 + n], s);
                if (s > mw) { sw = sw * __expf(mw - s) + 1.0f; mw = s; }
                else        { sw += __expf(s - mw); }
            }
        }
        if (lane == 0) { wpm[w4] = mw; wps[w4] = sw; }
        __syncthreads();
        if (tid == 0) {
            float M = -3.4e38f, S = 0.f;
#pragma unroll
            for (int k = 0; k < 4; ++k) {
                float Mn = fmaxf(M, wpm[k]);
                S = S * __expf(M - Mn) + wps[k] * __expf(wpm[k] - Mn);
                M = Mn;
            }
            if (bid == 0) {                  // fold u0 (from k_fuseA)
                float t0 = logits[0];
                float Mn = fmaxf(M, t0);
                S = S * __expf(M - Mn) + __expf(t0 - Mn);
                M = Mn;
            }
            astore(&pm[bid], M); astore(&ps[bid], S);
        }
    }
    gbar(cntB, 1024);

    // ---- P2: block 0 reduces 1024 partials ----
    if (bid == 0) {
        float M = -3.4e38f, S = 0.f;
#pragma unroll
        for (int k = 0; k < 4; ++k) {
            int i = tid * 4 + k;
            float m2 = aload(&pm[i]), s2 = aload(&ps[i]);
            float Mn = fmaxf(M, m2);
            S = S * __expf(M - Mn) + s2 * __expf(m2 - Mn);
            M = Mn;
        }
        for (int off = 1; off < 64; off <<= 1) {
            float m2 = __shfl_xor(M, off, 64);
            float s2 = __shfl_xor(S, off, 64);
            float Mn = fmaxf(M, m2);
            S = S * __expf(M - Mn) + s2 * __expf(m2 - Mn);
            M = Mn;
        }
        if (lane == 0) { rm[w4] = M; rs[w4] = S; }
        __syncthreads();
        if (tid == 0) {
            float Mf = -3.4e38f, Sf = 0.f;
#pragma unroll
            for (int k = 0; k < 4; ++k) {
                float Mn = fmaxf(Mf, rm[k]);
                Sf = Sf * __expf(Mf - Mn) + rs[k] * __expf(rm[k] - Mn);
                Mf = Mn;
            }
            astore(&scal[1], Mf); astore(&scal[2], Sf);
        }
    }
    gbar(cntB, 2048);

    // ---- P3: write softmax ----
    {
        float M = aload(&scal[1]), S = aload(&scal[2]);
        if (tid < 32) {
            int n = bid * 32 + tid;
            out[1 + n] = __expf(aload(&logits[1 + n]) - M) / S;
        }
        if (bid == 0 && tid == 32)
            out[0] = __expf(logits[0] - M) / S;
    }
}

extern "C" void kernel_launch(void* const* d_in, const int* in_sizes, int n_in,
                              void* d_out, int out_size, void* d_ws, size_t ws_size,
                              hipStream_t stream) {
    const float* query = (const float*)d_in[0];
    const float* pn    = (const float*)d_in[1];
    const float* nb    = (const float*)d_in[2];
    const int*   aid   = (const int*)d_in[3];
    const float* Wih   = (const float*)d_in[4];
    const float* Whh   = (const float*)d_in[5];
    const float* bih   = (const float*)d_in[6];
    const float* bhh   = (const float*)d_in[7];
    const float* Wfa   = (const float*)d_in[8];
    const float* bfa   = (const float*)d_in[9];
    const float* Wfs   = (const float*)d_in[10];
    const float* bfs   = (const float*)d_in[11];
    const float* Wfp   = (const float*)d_in[12];
    const float* bfp   = (const float*)d_in[13];

    float* ws = (float*)d_ws;
    unsigned short* wh2   = (unsigned short*)(ws + WS_WH2);
    unsigned*       hmaxk = (unsigned*)(ws + WS_HMAXK);
    unsigned*       cnts  = (unsigned*)(ws + WS_CNT);
    float* hsel   = ws + WS_HSEL;
    float* gi     = ws + WS_GI;
    float* hbuf   = ws + WS_HBUF;
    float* hs_ws  = ws + WS_HS;
    float* scal   = ws + WS_SCAL;
    float* pm     = ws + WS_PM;
    float* psum   = ws + WS_PS;
    float* logits = ws + WS_LOGITS;
    float* hnts7  = ws + WS_HNTS7;
    float* out    = (float*)d_out;

    k_prep <<<(KT * 128 * 8 + 255) / 256, 256, 0, stream>>>(Wfa, wh2, hmaxk, cnts);
    k_big  <<<L * 256, 256, 0, stream>>>(nb, wh2, bfa, aid, hmaxk, hsel, hnts7);
    k_fuseA<<<303, 256, 0, stream>>>(Wih, bih, pn, hmaxk, hsel, Whh, bhh, query,
                                     Wfs, bfs, Wfp, bfp, gi, hbuf, hs_ws, logits, cnts);
    k_fuseB<<<1024, 256, 0, stream>>>(hnts7, hs_ws, logits, pm, psum, scal, out, cnts);
}

// Round 12
// 283.659 us; speedup vs baseline: 1.6878x; 1.6878x over previous
//
#include <hip/hip_runtime.h>
#include <math.h>

#define L 8
#define N 32768
#define H 404
#define D 128
#define F 532
#define KT 9              // K-tiles of 64 (64*9=576; B cols >= 532 are zero)
#define GRU_BLOCKS 101    // one wave per hidden index

typedef __attribute__((ext_vector_type(8))) _Float16 half8;
typedef __attribute__((ext_vector_type(4))) float f32x4;
typedef __attribute__((address_space(3))) unsigned int as3_u32;
typedef __attribute__((address_space(1))) unsigned int as1_u32;

// workspace layout (float offsets)
#define WS_WH3     0                        // 9*8*128 x 8 fp16 = 36864 floats
#define WS_HMAXK   (WS_WH3 + 36864)         // 8*128 uint keys
#define WS_HSEL    (WS_HMAXK + L * D)       // 7*128
#define WS_GI      (WS_HSEL + (L - 1) * D)  // 8*1212
#define WS_HBUF    (WS_GI + L * 3 * H)      // 2*404
#define WS_V       (WS_HBUF + 2 * H)        // 532
#define WS_HS      (WS_V + F)               // 128
#define WS_SCAL    (WS_HS + D)              // c, M, S, spare
#define WS_CNT     (WS_SCAL + 4)            // gru barrier counter
#define WS_LOGITS  (WS_CNT + 4)             // 32769

__device__ __forceinline__ unsigned encf(float f) {
    unsigned u = __float_as_uint(f);
    return (u & 0x80000000u) ? ~u : (u | 0x80000000u);
}
__device__ __forceinline__ float decf(unsigned u) {
    unsigned b = (u & 0x80000000u) ? (u ^ 0x80000000u) : ~u;
    return __uint_as_float(b);
}
__device__ __forceinline__ float sigmoidf_(float x) {
    return 1.0f / (1.0f + __expf(-x));
}
__device__ __forceinline__ unsigned pk_f16(float a, float b) {
    auto h = __builtin_amdgcn_cvt_pkrtz(a, b);
    return *(unsigned*)&h;
}
__device__ __forceinline__ half8 pack8(float4 x0, float4 x1) {
    uint4 u = { pk_f16(x0.x, x0.y), pk_f16(x0.z, x0.w),
                pk_f16(x1.x, x1.y), pk_f16(x1.z, x1.w) };
    return *(half8*)&u;
}
__device__ __forceinline__ void gld16(const void* g, void* l) {
    __builtin_amdgcn_global_load_lds((const as1_u32*)g, (as3_u32*)l, 16, 0, 0);
}

// ---- prep: B chunks wh3[((kt*8+c8)*128+col)*8+e] = W[col][kt*64+c8*8+e] ----
__global__ void k_prep(const float* __restrict__ Wfa, unsigned short* __restrict__ wh3,
                       unsigned* __restrict__ keys, unsigned* __restrict__ cnt) {
    int i = blockIdx.x * 256 + threadIdx.x;
    if (i < L * D) keys[i] = 0u;           // decodes below all finite values
    if (i == 2000) *cnt = 0u;
    if (i >= KT * 8 * 128) return;
    int kt = i >> 10;
    int rem = i & 1023;
    int c8 = rem >> 7, col = rem & 127;
    int k0 = kt * 64 + c8 * 8;
    unsigned short v[8];
#pragma unroll
    for (int e = 0; e < 8; ++e) {
        int k = k0 + e;
        float x = (k < F) ? Wfa[col * F + k] : 0.0f;
        _Float16 h = (_Float16)x;
        v[e] = *(unsigned short*)&h;
    }
    *(uint4*)(wh3 + (long)i * 8) = *(uint4*)v;
}

// ---- big einsum: async A staging (32 KB LDS), B direct from L2; 4 blocks/CU ----
// grid 2048: l = bid>>8, 128-row chunk = bid&255. 4 waves, each 64x64 output.
__global__ __launch_bounds__(256, 4)
void k_big(const float* __restrict__ nb, const unsigned short* __restrict__ wh3,
           const float* __restrict__ bfa, const int* __restrict__ aid,
           unsigned* __restrict__ hmaxk, float* __restrict__ hsel) {
    __shared__ float As[128 * 64];          // 32 KB, row = 256 B = 16 chunks

    const int bid = blockIdx.x;
    const int l_hop = bid >> 8;
    const int row0 = (bid & 255) * 128;
    const int tid = threadIdx.x;
    const int lane = tid & 63, w = tid >> 6;
    const int wm = w >> 1, wn = w & 1;
    const int lr = lane & 15, kg = lane >> 4;

    const float* xbase = nb + ((long)l_hop * N + row0) * F;

    f32x4 acc[4][4];
    float bv[4];
#pragma unroll
    for (int n = 0; n < 4; ++n) bv[n] = bfa[wn * 64 + n * 16 + lr];
#pragma unroll
    for (int m = 0; m < 4; ++m)
#pragma unroll
        for (int n = 0; n < 4; ++n) {
            acc[m][n][0] = bv[n]; acc[m][n][1] = bv[n];
            acc[m][n][2] = bv[n]; acc[m][n][3] = bv[n];
        }

    const int srow = lane >> 4;        // A-stage: sub-row within 4-row group
    const int scp  = lane & 15;        // A-stage: dest chunk

    for (int kt = 0; kt < KT; ++kt) {
        const int fc = kt * 64;
        __syncthreads();               // prior MFMA reads done -> LDS writable

        // ---- stage A: 8 async issues/thread; dest linear, source pre-swizzled ----
#pragma unroll
        for (int it = 0; it < 8; ++it) {
            int rbase = it * 16 + w * 4;
            int row = rbase + srow;
            int cg = scp ^ (row & 7);
            int col0 = fc + cg * 4;
            const float* src = xbase + (long)row * F + ((col0 < F) ? col0 : 0);
            gld16(src, (char*)As + rbase * 256);
        }
        __syncthreads();               // vmcnt(0) drained by compiler before barrier

        // ---- 2 K-steps of 32: B direct from L2, A swizzled LDS, cvt on consume ----
#pragma unroll
        for (int ks = 0; ks < 2; ++ks) {
            half8 b[4];
#pragma unroll
            for (int n = 0; n < 4; ++n) {
                long bo = (((long)kt * 8 + ks * 4 + kg) * 128 + wn * 64 + n * 16 + lr) * 8;
                b[n] = *(const half8*)(wh3 + bo);
            }
#pragma unroll
            for (int m = 0; m < 4; ++m) {
                int row = wm * 64 + m * 16 + lr;
                int c0 = ks * 8 + kg * 2;
                const char* base = (const char*)As + row * 256;
                float4 x0 = *(const float4*)(base + (((c0)     ^ (row & 7)) << 4));
                float4 x1 = *(const float4*)(base + (((c0 + 1) ^ (row & 7)) << 4));
                half8 a = pack8(x0, x1);
#pragma unroll
                for (int n = 0; n < 4; ++n)
                    acc[m][n] = __builtin_amdgcn_mfma_f32_16x16x32_f16(a, b[n], acc[m][n], 0, 0, 0);
            }
        }
    }

    __syncthreads();   // LDS reads done; reuse As for cross-wave max

    // selected-action row (compile-time acc indexing)
    if (l_hop < L - 1) {
        int br = aid[l_hop] - row0;
        if (br >= 0 && br < 128 && (br >> 6) == wm && ((br >> 2) & 3) == kg) {
            int msel = (br >> 4) & 3, rsel = br & 3;
#pragma unroll
            for (int n = 0; n < 4; ++n) {
                float vsel = 0.f;
#pragma unroll
                for (int m = 0; m < 4; ++m)
#pragma unroll
                    for (int r = 0; r < 4; ++r)
                        if (m == msel && r == rsel) vsel = acc[m][n][r];
                hsel[l_hop * D + wn * 64 + n * 16 + lr] = vsel;
            }
        }
    }

    // column max: thread-local -> cross-lane-group shfl -> cross-wave LDS -> atomic
    float cmax[4];
#pragma unroll
    for (int n = 0; n < 4; ++n) {
        float m0 = acc[0][n][0];
#pragma unroll
        for (int m = 0; m < 4; ++m)
#pragma unroll
            for (int r = 0; r < 4; ++r) m0 = fmaxf(m0, acc[m][n][r]);
        m0 = fmaxf(m0, __shfl_xor(m0, 16, 64));
        m0 = fmaxf(m0, __shfl_xor(m0, 32, 64));
        cmax[n] = m0;
    }
    float* wmaxp = (float*)As;   // [2][128]
    if (kg == 0) {
#pragma unroll
        for (int n = 0; n < 4; ++n)
            wmaxp[wm * 128 + wn * 64 + n * 16 + lr] = cmax[n];
    }
    __syncthreads();
    if (tid < 128) {
        float mval = fmaxf(wmaxp[tid], wmaxp[128 + tid]);
        atomicMax(&hmaxk[l_hop * D + tid], encf(mval));
    }
}

// ---- gi for all 8 GRU steps: one wave per output row, coalesced W_ih reads ----
__global__ void k_gi(const float* __restrict__ Wih, const float* __restrict__ bih,
                     const float* __restrict__ pn, const unsigned* __restrict__ hmaxk,
                     const float* __restrict__ hsel, float* __restrict__ gi) {
    __shared__ float xs[L][3 * D];
    const int tid = threadIdx.x;
    for (int i = tid; i < L * 3 * D; i += 256) {
        int t = i / (3 * D), k = i % (3 * D);
        float x;
        if (t == 0) {
            x = (k < 2 * D) ? 0.0f : pn[k - 2 * D];
        } else {
            if (k < D)            x = decf(hmaxk[(t - 1) * D + k]);
            else if (k < 2 * D)   x = hsel[(t - 1) * D + (k - D)];
            else                  x = pn[t * D + (k - 2 * D)];
        }
        xs[t][k] = x;
    }
    __syncthreads();

    const int lane = tid & 63;
    const int row = blockIdx.x * 4 + (tid >> 6);   // 0..1211
    const float* wr = Wih + (long)row * 3 * D;
    float s[L];
#pragma unroll
    for (int t = 0; t < L; ++t) s[t] = 0.f;
#pragma unroll
    for (int c = 0; c < 6; ++c) {
        int k = lane + c * 64;
        float wv = wr[k];
#pragma unroll
        for (int t = 0; t < L; ++t) s[t] = fmaf(wv, xs[t][k], s[t]);
    }
#pragma unroll
    for (int t = 0; t < L; ++t)
        for (int off = 1; off < 64; off <<= 1) s[t] += __shfl_xor(s[t], off, 64);
    if (lane == 0) {
        float b = bih[row];
#pragma unroll
        for (int t = 0; t < L; ++t) gi[t * 3 * H + row] = s[t] + b;
    }
}

// ---- all 8 GRU steps in ONE kernel; one wave per hidden j; grid barrier ----
__global__ __launch_bounds__(256, 1)
void k_gru(const float* __restrict__ Whh, const float* __restrict__ bhh,
           const float* __restrict__ gi, const float* __restrict__ query,
           float* __restrict__ hbuf, unsigned* __restrict__ cnt) {
    const int tid = threadIdx.x;
    const int lane = tid & 63;
    const int j = blockIdx.x * 4 + (tid >> 6);     // 0..403

    float wr[7], wz[7], wnn[7];
#pragma unroll
    for (int c = 0; c < 7; ++c) {
        int i = lane + c * 64;
        bool ok = i < H;
        wr[c]  = ok ? Whh[(long)j * H + i]           : 0.f;
        wz[c]  = ok ? Whh[(long)(H + j) * H + i]     : 0.f;
        wnn[c] = ok ? Whh[(long)(2 * H + j) * H + i] : 0.f;
    }
    float b_r = 0.f, b_z = 0.f, b_n = 0.f;
    if (lane == 0) { b_r = bhh[j]; b_z = bhh[H + j]; b_n = bhh[2 * H + j]; }

    for (int t = 0; t < L; ++t) {
        const float* hin = (t == 0) ? query : (hbuf + ((t - 1) & 1) * H);
        float* hout = hbuf + (t & 1) * H;
        float pr = 0.f, pz = 0.f, pn2 = 0.f;
#pragma unroll
        for (int c = 0; c < 7; ++c) {
            int i = lane + c * 64;
            float hv = 0.f;
            if (i < H)
                hv = (t == 0) ? hin[i]
                              : __hip_atomic_load(hin + i, __ATOMIC_RELAXED,
                                                  __HIP_MEMORY_SCOPE_AGENT);
            pr  = fmaf(wr[c],  hv, pr);
            pz  = fmaf(wz[c],  hv, pz);
            pn2 = fmaf(wnn[c], hv, pn2);
        }
        for (int off = 1; off < 64; off <<= 1) {
            pr  += __shfl_xor(pr, off, 64);
            pz  += __shfl_xor(pz, off, 64);
            pn2 += __shfl_xor(pn2, off, 64);
        }
        if (lane == 0) {
            const float* gt = gi + t * 3 * H;
            float hprev = (t == 0) ? hin[j]
                                   : __hip_atomic_load(hin + j, __ATOMIC_RELAXED,
                                                       __HIP_MEMORY_SCOPE_AGENT);
            float r  = sigmoidf_(gt[j] + pr + b_r);
            float z  = sigmoidf_(gt[H + j] + pz + b_z);
            float nn = tanhf(gt[2 * H + j] + r * (pn2 + b_n));
            float hv = (1.0f - z) * nn + z * hprev;
            __hip_atomic_store(hout + j, hv, __ATOMIC_RELAXED,
                               __HIP_MEMORY_SCOPE_AGENT);
        }
        if (t < L - 1) {
            __syncthreads();
            if (tid == 0) {
                __hip_atomic_fetch_add(cnt, 1u, __ATOMIC_RELEASE,
                                       __HIP_MEMORY_SCOPE_AGENT);
                unsigned target = (unsigned)GRU_BLOCKS * (t + 1);
                while (__hip_atomic_load(cnt, __ATOMIC_ACQUIRE,
                                         __HIP_MEMORY_SCOPE_AGENT) < target)
                    __builtin_amdgcn_s_sleep(2);
            }
            __syncthreads();
        }
    }
}

// ---- hSt + v + u0 + c in one block (1024 thr, 16 waves) ----
__global__ void k_final(const float* __restrict__ qt, const float* __restrict__ Wfs,
                        const float* __restrict__ bfs, const float* __restrict__ Wfp,
                        const float* __restrict__ bfp, const float* __restrict__ bfa,
                        const float* __restrict__ Wfa, const unsigned* __restrict__ hmaxk,
                        float* __restrict__ v, float* __restrict__ scal,
                        float* __restrict__ logits) {
    __shared__ float hs[D];
    int tid = threadIdx.x, lane = tid & 63, wid = tid >> 6;
#pragma unroll
    for (int dd = 0; dd < 8; ++dd) {
        int d = wid * 8 + dd;
        float s = 0.f;
#pragma unroll
        for (int c = 0; c < 7; ++c) {
            int i = lane + c * 64;
            if (i < H) s = fmaf(qt[i], Wfs[(long)d * H + i], s);
        }
        for (int off = 1; off < 64; off <<= 1) s += __shfl_xor(s, off, 64);
        if (lane == 0) hs[d] = s + bfs[d];
    }
    __syncthreads();
    if (tid < F) {
        float s = 0.f;
#pragma unroll 16
        for (int d = 0; d < D; ++d) s = fmaf(hs[d], Wfa[(long)d * F + tid], s);
        v[tid] = s;
    } else if (tid == F) {
        float s = bfp[0];
        for (int d = 0; d < D; ++d) {
            s = fmaf(hs[d], Wfp[d], s);
            s = fmaf(decf(hmaxk[(L - 1) * D + d]), Wfp[D + d], s);
        }
        logits[0] = s;
    } else if (tid == F + 1) {
        float c2 = 0.f;
        for (int d = 0; d < D; ++d) c2 = fmaf(hs[d], bfa[d], c2);
        scal[0] = c2;
    }
}

// ---- uks logits (exact fp32 path); one wave per neighbor row of hop 7 ----
__global__ void k_uks(const float* __restrict__ nb7, const float* __restrict__ v,
                      const float* __restrict__ scal, float* __restrict__ logits) {
    long n = (long)blockIdx.x * 4 + (threadIdx.x >> 6);
    int lane = threadIdx.x & 63;
    const float* row = nb7 + n * F;
    float s = 0.f;
    for (int f = lane; f < F; f += 64) s = fmaf(v[f], row[f], s);
    for (int off = 1; off < 64; off <<= 1) s += __shfl_xor(s, off, 64);
    if (lane == 0) logits[1 + n] = s + scal[0];
}

// ---- softmax reduce over 32769 (single block, 1024 thr) ----
__global__ void k_sm12(const float* __restrict__ logits, float* __restrict__ scal) {
    __shared__ float sm[16], ss[16];
    int tid = threadIdx.x, lane = tid & 63, wid = tid >> 6;
    float m = -3.4e38f, s = 0.f;
    for (int i = tid; i <= N; i += 1024) {
        float x = logits[i];
        if (x > m) { s = s * __expf(m - x) + 1.0f; m = x; }
        else       { s += __expf(x - m); }
    }
    for (int off = 1; off < 64; off <<= 1) {
        float m2 = __shfl_xor(m, off, 64);
        float s2 = __shfl_xor(s, off, 64);
        float M = fmaxf(m, m2);
        s = s * __expf(m - M) + s2 * __expf(m2 - M);
        m = M;
    }
    if (lane == 0) { sm[wid] = m; ss[wid] = s; }
    __syncthreads();
    if (tid == 0) {
        float M = sm[0], S = 0.f;
        for (int k = 1; k < 16; ++k) M = fmaxf(M, sm[k]);
        for (int k = 0; k < 16; ++k) S += ss[k] * __expf(sm[k] - M);
        scal[1] = M; scal[2] = S;
    }
}

__global__ void k_sm3(const float* __restrict__ logits, const float* __restrict__ scal,
                      float* __restrict__ out) {
    int i = blockIdx.x * 256 + threadIdx.x;
    if (i <= N) out[i] = __expf(logits[i] - scal[1]) / scal[2];
}

extern "C" void kernel_launch(void* const* d_in, const int* in_sizes, int n_in,
                              void* d_out, int out_size, void* d_ws, size_t ws_size,
                              hipStream_t stream) {
    const float* query = (const float*)d_in[0];
    const float* pn    = (const float*)d_in[1];
    const float* nb    = (const float*)d_in[2];
    const int*   aid   = (const int*)d_in[3];
    const float* Wih   = (const float*)d_in[4];
    const float* Whh   = (const float*)d_in[5];
    const float* bih   = (const float*)d_in[6];
    const float* bhh   = (const float*)d_in[7];
    const float* Wfa   = (const float*)d_in[8];
    const float* bfa   = (const float*)d_in[9];
    const float* Wfs   = (const float*)d_in[10];
    const float* bfs   = (const float*)d_in[11];
    const float* Wfp   = (const float*)d_in[12];
    const float* bfp   = (const float*)d_in[13];

    float* ws = (float*)d_ws;
    unsigned short* wh3   = (unsigned short*)(ws + WS_WH3);
    unsigned*       hmaxk = (unsigned*)(ws + WS_HMAXK);
    unsigned*       cnt   = (unsigned*)(ws + WS_CNT);
    float* hsel   = ws + WS_HSEL;
    float* gi     = ws + WS_GI;
    float* hbuf   = ws + WS_HBUF;
    float* v      = ws + WS_V;
    float* scal   = ws + WS_SCAL;
    float* logits = ws + WS_LOGITS;
    float* out    = (float*)d_out;

    k_prep<<<(KT * 8 * 128 + 255) / 256, 256, 0, stream>>>(Wfa, wh3, hmaxk, cnt);
    k_big <<<L * 256, 256, 0, stream>>>(nb, wh3, bfa, aid, hmaxk, hsel);
    k_gi  <<<303, 256, 0, stream>>>(Wih, bih, pn, hmaxk, hsel, gi);
    k_gru <<<GRU_BLOCKS, 256, 0, stream>>>(Whh, bhh, gi, query, hbuf, cnt);

    const float* qt = hbuf + ((L - 1) & 1) * H;   // hbuf[1]
    k_final<<<1, 1024, 0, stream>>>(qt, Wfs, bfs, Wfp, bfp, bfa, Wfa, hmaxk, v, scal, logits);
    k_uks  <<<N / 4, 256, 0, stream>>>(nb + (long)(L - 1) * N * F, v, scal, logits);

    k_sm12<<<1, 1024, 0, stream>>>(logits, scal);
    k_sm3 <<<(N + 1 + 255) / 256, 256, 0, stream>>>(logits, scal, out);
}

// Round 13
// 256.564 us; speedup vs baseline: 1.8661x; 1.1056x over previous
//
#include <hip/hip_runtime.h>
#include <math.h>

#define L 8
#define N 32768
#define H 404
#define D 128
#define F 532
#define NCH 133           // 16B chunks per row (532*4/16)
#define GRU_BLOCKS 101

typedef __attribute__((ext_vector_type(8))) _Float16 half8;
typedef __attribute__((ext_vector_type(4))) float f32x4;
typedef __attribute__((address_space(3))) unsigned int as3_u32;
typedef __attribute__((address_space(1))) unsigned int as1_u32;

// workspace layout (float offsets)
#define WS_WH3     0                        // 72 chunks x 128 cols x 8 fp16 = 36864 floats
#define WS_HMAXK   (WS_WH3 + 36864)         // 8*128 uint keys
#define WS_HSEL    (WS_HMAXK + L * D)       // 7*128
#define WS_GI      (WS_HSEL + (L - 1) * D)  // 8*1212
#define WS_HBUF    (WS_GI + L * 3 * H)      // 2*404
#define WS_V       (WS_HBUF + 2 * H)        // 532
#define WS_HS      (WS_V + F)               // 128
#define WS_SCAL    (WS_HS + D)              // c, M, S, spare
#define WS_CNT     (WS_SCAL + 4)            // gru barrier counter
#define WS_LOGITS  (WS_CNT + 4)             // 32769

__device__ __forceinline__ unsigned encf(float f) {
    unsigned u = __float_as_uint(f);
    return (u & 0x80000000u) ? ~u : (u | 0x80000000u);
}
__device__ __forceinline__ float decf(unsigned u) {
    unsigned b = (u & 0x80000000u) ? (u ^ 0x80000000u) : ~u;
    return __uint_as_float(b);
}
__device__ __forceinline__ float sigmoidf_(float x) {
    return 1.0f / (1.0f + __expf(-x));
}
__device__ __forceinline__ unsigned pk_f16(float a, float b) {
    auto h = __builtin_amdgcn_cvt_pkrtz(a, b);
    return *(unsigned*)&h;
}
__device__ __forceinline__ half8 pack8(float4 x0, float4 x1) {
    uint4 u = { pk_f16(x0.x, x0.y), pk_f16(x0.z, x0.w),
                pk_f16(x1.x, x1.y), pk_f16(x1.z, x1.w) };
    return *(half8*)&u;
}
__device__ __forceinline__ void gld16(const void* g, void* l) {
    __builtin_amdgcn_global_load_lds((const as1_u32*)g, (as3_u32*)l, 16, 0, 0);
}

// ---- prep: B chunks wh3[(c8*128+col)*8+e] = W[col][c8*8+e], c8 in 0..71 ----
__global__ void k_prep(const float* __restrict__ Wfa, unsigned short* __restrict__ wh3,
                       unsigned* __restrict__ keys, unsigned* __restrict__ cnt) {
    int i = blockIdx.x * 256 + threadIdx.x;
    if (i < L * D) keys[i] = 0u;
    if (i == 2000) *cnt = 0u;
    if (i >= 72 * 128) return;
    int c8 = i >> 7, col = i & 127;
    int k0 = c8 * 8;
    unsigned short v[8];
#pragma unroll
    for (int e = 0; e < 8; ++e) {
        int k = k0 + e;
        float x = (k < F) ? Wfa[col * F + k] : 0.0f;
        _Float16 h = (_Float16)x;
        v[e] = *(unsigned short*)&h;
    }
    *(uint4*)(wh3 + (long)i * 8) = *(uint4*)v;
}

// ---- big einsum: 32-row blocks, ONE sequential whole-K async stage ----
// grid 8192: l = bid>>10, 32-row chunk = bid&1023. 4 waves, each 32 rows x 32 cols.
__global__ __launch_bounds__(256, 2)
void k_big(const float* __restrict__ nb, const unsigned short* __restrict__ wh3,
           const float* __restrict__ bfa, const int* __restrict__ aid,
           unsigned* __restrict__ hmaxk, float* __restrict__ hsel) {
    __shared__ float As[32 * NCH * 4 + 16];   // 68096 B data + 64 B zero pad

    const int bid = blockIdx.x;
    const int l_hop = bid >> 10;
    const int row0 = (bid & 1023) * 32;
    const int tid = threadIdx.x;
    const int lane = tid & 63, w = tid >> 6;
    const int lr = lane & 15, kg = lane >> 4;

    const char* xb = (const char*)(nb + ((long)l_hop * N + row0) * F);

    // zero the 64B tail pad (read by ks=16 kg>=2 on row 31; x * B_zero = 0)
    if (tid < 16) As[32 * NCH * 4 + tid] = 0.0f;

    // ---- stage: 4256 chunks, fully sequential global order, linear LDS ----
    // wave-chunk idx = it*4 + w covers chunks [idx*64, idx*64+64)
#pragma unroll
    for (int it = 0; it < 17; ++it) {
        int idx = it * 4 + w;
        if (idx < 66) {
            gld16(xb + (long)idx * 1024 + lane * 16, (char*)As + idx * 1024);
        } else if (idx == 66) {
            if (lane < 32)
                gld16(xb + 66 * 1024 + lane * 16, (char*)As + 66 * 1024);
        }
    }

    // acc init = bias
    f32x4 acc[2][2];
    float bv[2];
#pragma unroll
    for (int n = 0; n < 2; ++n) bv[n] = bfa[w * 32 + n * 16 + lr];
#pragma unroll
    for (int m = 0; m < 2; ++m)
#pragma unroll
        for (int n = 0; n < 2; ++n) {
            acc[m][n][0] = bv[n]; acc[m][n][1] = bv[n];
            acc[m][n][2] = bv[n]; acc[m][n][3] = bv[n];
        }

    __syncthreads();   // drains all global_load_lds (compiler emits vmcnt(0))

    // ---- 17 K-steps of 32; no barriers; B direct from L2-hot wh3 ----
#pragma unroll 2
    for (int ks = 0; ks < 17; ++ks) {
        half8 b[2];
#pragma unroll
        for (int n = 0; n < 2; ++n) {
            long bo = (((long)ks * 4 + kg) * 128 + w * 32 + n * 16 + lr) * 8;
            b[n] = *(const half8*)(wh3 + bo);
        }
#pragma unroll
        for (int m = 0; m < 2; ++m) {
            int row = m * 16 + lr;
            const char* base = (const char*)As + row * 2128 + ks * 128 + kg * 32;
            float4 x0 = *(const float4*)(base);
            float4 x1 = *(const float4*)(base + 16);
            half8 a = pack8(x0, x1);
#pragma unroll
            for (int n = 0; n < 2; ++n)
                acc[m][n] = __builtin_amdgcn_mfma_f32_16x16x32_f16(a, b[n], acc[m][n], 0, 0, 0);
        }
    }

    // ---- selected-action row ----
    if (l_hop < L - 1) {
        int br = aid[l_hop] - row0;
        if (br >= 0 && br < 32 && ((br >> 2) & 3) == kg) {
            int msel = (br >> 4) & 1, rsel = br & 3;
#pragma unroll
            for (int n = 0; n < 2; ++n) {
                float vsel = 0.f;
#pragma unroll
                for (int m = 0; m < 2; ++m)
#pragma unroll
                    for (int r = 0; r < 4; ++r)
                        if (m == msel && r == rsel) vsel = acc[m][n][r];
                hsel[l_hop * D + w * 32 + n * 16 + lr] = vsel;
            }
        }
    }

    // ---- column max: wave owns its 32 cols -> direct atomicMax ----
#pragma unroll
    for (int n = 0; n < 2; ++n) {
        float m0 = acc[0][n][0];
#pragma unroll
        for (int m = 0; m < 2; ++m)
#pragma unroll
            for (int r = 0; r < 4; ++r) m0 = fmaxf(m0, acc[m][n][r]);
        m0 = fmaxf(m0, __shfl_xor(m0, 16, 64));
        m0 = fmaxf(m0, __shfl_xor(m0, 32, 64));
        if (kg == 0)
            atomicMax(&hmaxk[l_hop * D + w * 32 + n * 16 + lr], encf(m0));
    }
}

// ---- gi for all 8 GRU steps (unchanged r9) ----
__global__ void k_gi(const float* __restrict__ Wih, const float* __restrict__ bih,
                     const float* __restrict__ pn, const unsigned* __restrict__ hmaxk,
                     const float* __restrict__ hsel, float* __restrict__ gi) {
    __shared__ float xs[L][3 * D];
    const int tid = threadIdx.x;
    for (int i = tid; i < L * 3 * D; i += 256) {
        int t = i / (3 * D), k = i % (3 * D);
        float x;
        if (t == 0) {
            x = (k < 2 * D) ? 0.0f : pn[k - 2 * D];
        } else {
            if (k < D)            x = decf(hmaxk[(t - 1) * D + k]);
            else if (k < 2 * D)   x = hsel[(t - 1) * D + (k - D)];
            else                  x = pn[t * D + (k - 2 * D)];
        }
        xs[t][k] = x;
    }
    __syncthreads();

    const int lane = tid & 63;
    const int row = blockIdx.x * 4 + (tid >> 6);
    const float* wr = Wih + (long)row * 3 * D;
    float s[L];
#pragma unroll
    for (int t = 0; t < L; ++t) s[t] = 0.f;
#pragma unroll
    for (int c = 0; c < 6; ++c) {
        int k = lane + c * 64;
        float wv = wr[k];
#pragma unroll
        for (int t = 0; t < L; ++t) s[t] = fmaf(wv, xs[t][k], s[t]);
    }
#pragma unroll
    for (int t = 0; t < L; ++t)
        for (int off = 1; off < 64; off <<= 1) s[t] += __shfl_xor(s[t], off, 64);
    if (lane == 0) {
        float b = bih[row];
#pragma unroll
        for (int t = 0; t < L; ++t) gi[t * 3 * H + row] = s[t] + b;
    }
}

// ---- 8 GRU steps in one kernel (unchanged r9) ----
__global__ __launch_bounds__(256, 1)
void k_gru(const float* __restrict__ Whh, const float* __restrict__ bhh,
           const float* __restrict__ gi, const float* __restrict__ query,
           float* __restrict__ hbuf, unsigned* __restrict__ cnt) {
    const int tid = threadIdx.x;
    const int lane = tid & 63;
    const int j = blockIdx.x * 4 + (tid >> 6);

    float wr[7], wz[7], wnn[7];
#pragma unroll
    for (int c = 0; c < 7; ++c) {
        int i = lane + c * 64;
        bool ok = i < H;
        wr[c]  = ok ? Whh[(long)j * H + i]           : 0.f;
        wz[c]  = ok ? Whh[(long)(H + j) * H + i]     : 0.f;
        wnn[c] = ok ? Whh[(long)(2 * H + j) * H + i] : 0.f;
    }
    float b_r = 0.f, b_z = 0.f, b_n = 0.f;
    if (lane == 0) { b_r = bhh[j]; b_z = bhh[H + j]; b_n = bhh[2 * H + j]; }

    for (int t = 0; t < L; ++t) {
        const float* hin = (t == 0) ? query : (hbuf + ((t - 1) & 1) * H);
        float* hout = hbuf + (t & 1) * H;
        float pr = 0.f, pz = 0.f, pn2 = 0.f;
#pragma unroll
        for (int c = 0; c < 7; ++c) {
            int i = lane + c * 64;
            float hv = 0.f;
            if (i < H)
                hv = (t == 0) ? hin[i]
                              : __hip_atomic_load(hin + i, __ATOMIC_RELAXED,
                                                  __HIP_MEMORY_SCOPE_AGENT);
            pr  = fmaf(wr[c],  hv, pr);
            pz  = fmaf(wz[c],  hv, pz);
            pn2 = fmaf(wnn[c], hv, pn2);
        }
        for (int off = 1; off < 64; off <<= 1) {
            pr  += __shfl_xor(pr, off, 64);
            pz  += __shfl_xor(pz, off, 64);
            pn2 += __shfl_xor(pn2, off, 64);
        }
        if (lane == 0) {
            const float* gt = gi + t * 3 * H;
            float hprev = (t == 0) ? hin[j]
                                   : __hip_atomic_load(hin + j, __ATOMIC_RELAXED,
                                                       __HIP_MEMORY_SCOPE_AGENT);
            float r  = sigmoidf_(gt[j] + pr + b_r);
            float z  = sigmoidf_(gt[H + j] + pz + b_z);
            float nn = tanhf(gt[2 * H + j] + r * (pn2 + b_n));
            float hv = (1.0f - z) * nn + z * hprev;
            __hip_atomic_store(hout + j, hv, __ATOMIC_RELAXED,
                               __HIP_MEMORY_SCOPE_AGENT);
        }
        if (t < L - 1) {
            __syncthreads();
            if (tid == 0) {
                __hip_atomic_fetch_add(cnt, 1u, __ATOMIC_RELEASE,
                                       __HIP_MEMORY_SCOPE_AGENT);
                unsigned target = (unsigned)GRU_BLOCKS * (t + 1);
                while (__hip_atomic_load(cnt, __ATOMIC_ACQUIRE,
                                         __HIP_MEMORY_SCOPE_AGENT) < target)
                    __builtin_amdgcn_s_sleep(2);
            }
            __syncthreads();
        }
    }
}

// ---- hSt + v + u0 + c (unchanged r9) ----
__global__ void k_final(const float* __restrict__ qt, const float* __restrict__ Wfs,
                        const float* __restrict__ bfs, const float* __restrict__ Wfp,
                        const float* __restrict__ bfp, const float* __restrict__ bfa,
                        const float* __restrict__ Wfa, const unsigned* __restrict__ hmaxk,
                        float* __restrict__ v, float* __restrict__ scal,
                        float* __restrict__ logits) {
    __shared__ float hs[D];
    int tid = threadIdx.x, lane = tid & 63, wid = tid >> 6;
#pragma unroll
    for (int dd = 0; dd < 8; ++dd) {
        int d = wid * 8 + dd;
        float s = 0.f;
#pragma unroll
        for (int c = 0; c < 7; ++c) {
            int i = lane + c * 64;
            if (i < H) s = fmaf(qt[i], Wfs[(long)d * H + i], s);
        }
        for (int off = 1; off < 64; off <<= 1) s += __shfl_xor(s, off, 64);
        if (lane == 0) hs[d] = s + bfs[d];
    }
    __syncthreads();
    if (tid < F) {
        float s = 0.f;
#pragma unroll 16
        for (int d = 0; d < D; ++d) s = fmaf(hs[d], Wfa[(long)d * F + tid], s);
        v[tid] = s;
    } else if (tid == F) {
        float s = bfp[0];
        for (int d = 0; d < D; ++d) {
            s = fmaf(hs[d], Wfp[d], s);
            s = fmaf(decf(hmaxk[(L - 1) * D + d]), Wfp[D + d], s);
        }
        logits[0] = s;
    } else if (tid == F + 1) {
        float c2 = 0.f;
        for (int d = 0; d < D; ++d) c2 = fmaf(hs[d], bfa[d], c2);
        scal[0] = c2;
    }
}

// ---- uks logits (unchanged r9) ----
__global__ void k_uks(const float* __restrict__ nb7, const float* __restrict__ v,
                      const float* __restrict__ scal, float* __restrict__ logits) {
    long n = (long)blockIdx.x * 4 + (threadIdx.x >> 6);
    int lane = threadIdx.x & 63;
    const float* row = nb7 + n * F;
    float s = 0.f;
    for (int f = lane; f < F; f += 64) s = fmaf(v[f], row[f], s);
    for (int off = 1; off < 64; off <<= 1) s += __shfl_xor(s, off, 64);
    if (lane == 0) logits[1 + n] = s + scal[0];
}

// ---- softmax (unchanged r9) ----
__global__ void k_sm12(const float* __restrict__ logits, float* __restrict__ scal) {
    __shared__ float sm[16], ss[16];
    int tid = threadIdx.x, lane = tid & 63, wid = tid >> 6;
    float m = -3.4e38f, s = 0.f;
    for (int i = tid; i <= N; i += 1024) {
        float x = logits[i];
        if (x > m) { s = s * __expf(m - x) + 1.0f; m = x; }
        else       { s += __expf(x - m); }
    }
    for (int off = 1; off < 64; off <<= 1) {
        float m2 = __shfl_xor(m, off, 64);
        float s2 = __shfl_xor(s, off, 64);
        float M = fmaxf(m, m2);
        s = s * __expf(m - M) + s2 * __expf(m2 - M);
        m = M;
    }
    if (lane == 0) { sm[wid] = m; ss[wid] = s; }
    __syncthreads();
    if (tid == 0) {
        float M = sm[0], S = 0.f;
        for (int k = 1; k < 16; ++k) M = fmaxf(M, sm[k]);
        for (int k = 0; k < 16; ++k) S += ss[k] * __expf(sm[k] - M);
        scal[1] = M; scal[2] = S;
    }
}

__global__ void k_sm3(const float* __restrict__ logits, const float* __restrict__ scal,
                      float* __restrict__ out) {
    int i = blockIdx.x * 256 + threadIdx.x;
    if (i <= N) out[i] = __expf(logits[i] - scal[1]) / scal[2];
}

extern "C" void kernel_launch(void* const* d_in, const int* in_sizes, int n_in,
                              void* d_out, int out_size, void* d_ws, size_t ws_size,
                              hipStream_t stream) {
    const float* query = (const float*)d_in[0];
    const float* pn    = (const float*)d_in[1];
    const float* nb    = (const float*)d_in[2];
    const int*   aid   = (const int*)d_in[3];
    const float* Wih   = (const float*)d_in[4];
    const float* Whh   = (const float*)d_in[5];
    const float* bih   = (const float*)d_in[6];
    const float* bhh   = (const float*)d_in[7];
    const float* Wfa   = (const float*)d_in[8];
    const float* bfa   = (const float*)d_in[9];
    const float* Wfs   = (const float*)d_in[10];
    const float* bfs   = (const float*)d_in[11];
    const float* Wfp   = (const float*)d_in[12];
    const float* bfp   = (const float*)d_in[13];

    float* ws = (float*)d_ws;
    unsigned short* wh3   = (unsigned short*)(ws + WS_WH3);
    unsigned*       hmaxk = (unsigned*)(ws + WS_HMAXK);
    unsigned*       cnt   = (unsigned*)(ws + WS_CNT);
    float* hsel   = ws + WS_HSEL;
    float* gi     = ws + WS_GI;
    float* hbuf   = ws + WS_HBUF;
    float* v      = ws + WS_V;
    float* scal   = ws + WS_SCAL;
    float* logits = ws + WS_LOGITS;
    float* out    = (float*)d_out;

    k_prep<<<(72 * 128 + 255) / 256, 256, 0, stream>>>(Wfa, wh3, hmaxk, cnt);
    k_big <<<L * 1024, 256, 0, stream>>>(nb, wh3, bfa, aid, hmaxk, hsel);
    k_gi  <<<303, 256, 0, stream>>>(Wih, bih, pn, hmaxk, hsel, gi);
    k_gru <<<GRU_BLOCKS, 256, 0, stream>>>(Whh, bhh, gi, query, hbuf, cnt);

    const float* qt = hbuf + ((L - 1) & 1) * H;
    k_final<<<1, 1024, 0, stream>>>(qt, Wfs, bfs, Wfp, bfp, bfa, Wfa, hmaxk, v, scal, logits);
    k_uks  <<<N / 4, 256, 0, stream>>>(nb + (long)(L - 1) * N * F, v, scal, logits);

    k_sm12<<<1, 1024, 0, stream>>>(logits, scal);
    k_sm3 <<<(N + 1 + 255) / 256, 256, 0, stream>>>(logits, scal, out);
}